// Round 8
// baseline (178.260 us; speedup 1.0000x reference)
//
#include <hip/hip_runtime.h>
#include <hip/hip_bf16.h>

#define DEVI __device__ __forceinline__

typedef __attribute__((ext_vector_type(8))) short bf16x8;
typedef __attribute__((ext_vector_type(4))) short bf16x4;
typedef __attribute__((ext_vector_type(4))) float f32x4;
typedef __attribute__((ext_vector_type(16))) float f32x16;

DEVI unsigned short f2bf(float f) {
    unsigned u = __float_as_uint(f);
    u += 0x7FFF + ((u >> 16) & 1);
    return (unsigned short)(u >> 16);
}
DEVI float bf2f(unsigned short h) {
    return __uint_as_float(((unsigned)h) << 16);
}
DEVI f32x4 mfma16(bf16x8 a, bf16x8 b, f32x4 c) {
    return __builtin_amdgcn_mfma_f32_16x16x32_bf16(a, b, c, 0, 0, 0);
}
DEVI f32x16 mfma32(bf16x8 a, bf16x8 b, f32x16 c) {
    return __builtin_amdgcn_mfma_f32_32x32x16_bf16(a, b, c, 0, 0, 0);
}
DEVI void gload_lds16(const void* g, void* l) {
    __builtin_amdgcn_global_load_lds(
        (const __attribute__((address_space(1))) unsigned int*)g,
        (__attribute__((address_space(3))) unsigned int*)l, 16, 0, 0);
}

// ---------------------------------------------------------------------------
// Prep: X f32 [4096*1024] -> bf16
// ---------------------------------------------------------------------------
__global__ __launch_bounds__(256) void k_cvt(
    const float* __restrict__ X, unsigned short* __restrict__ Xb)
{
    int i = blockIdx.x * 256 + threadIdx.x;
#pragma unroll
    for (int j = 0; j < 4; ++j) {
        int idx = i + j * 262144;
        float4 v = *(const float4*)(X + (size_t)idx * 4);
        bf16x4 hv;
        hv[0] = (short)f2bf(v.x); hv[1] = (short)f2bf(v.y);
        hv[2] = (short)f2bf(v.z); hv[3] = (short)f2bf(v.w);
        *(bf16x4*)(Xb + (size_t)idx * 4) = hv;
    }
}

// ---------------------------------------------------------------------------
// Prep: W f32 [1024][N] -> Wt bf16 [N][1024]  (transpose + convert)
// ---------------------------------------------------------------------------
__global__ __launch_bounds__(256) void k_wt(
    const float* __restrict__ W, unsigned short* __restrict__ Wt, int N)
{
    __shared__ unsigned short T[64][72];   // [n][k]
    const int tid = threadIdx.x;
    const int n0 = blockIdx.x * 64, k0 = blockIdx.y * 64;
#pragma unroll
    for (int j = 0; j < 4; ++j) {
        int idx = tid + j * 256;
        int kk = idx >> 4, c4 = (idx & 15) << 2;
        float4 v = *(const float4*)(W + (size_t)(k0 + kk) * N + n0 + c4);
        T[c4 + 0][kk] = f2bf(v.x); T[c4 + 1][kk] = f2bf(v.y);
        T[c4 + 2][kk] = f2bf(v.z); T[c4 + 3][kk] = f2bf(v.w);
    }
    __syncthreads();
#pragma unroll
    for (int j = 0; j < 4; ++j) {
        int idx = tid + j * 256;
        int n = idx >> 4, c4 = (idx & 15) << 2;
        *(bf16x4*)(Wt + (size_t)(n0 + n) * 1024 + k0 + c4) = *(bf16x4*)&T[n][c4];
    }
}

// ---------------------------------------------------------------------------
// GEMM1: qkv[4096][3072] bf16 = Xb[4096][1024] @ Wt1^T   (B^T layout, m97-style)
// ---------------------------------------------------------------------------
__global__ __launch_bounds__(256) void k_gemm1(
    const unsigned short* __restrict__ A, const unsigned short* __restrict__ B,
    unsigned short* __restrict__ C)
{
    __shared__ unsigned short As[128 * 64];
    __shared__ unsigned short Bs[128 * 64];
    const int tid = threadIdx.x, lane = tid & 63, wid = tid >> 6;
    const int wr = (wid >> 1) * 64, wc = (wid & 1) * 64;
    const int row0 = blockIdx.y * 128, col0 = blockIdx.x * 128;
    const int rsel = lane & 15, kgr = (lane >> 4) * 8;
    const int lr = lane >> 3, lc = (lane & 7) * 8;

    f32x4 acc[4][4];
#pragma unroll
    for (int i = 0; i < 4; ++i)
#pragma unroll
        for (int j = 0; j < 4; ++j) acc[i][j] = (f32x4){0.f, 0.f, 0.f, 0.f};

    for (int k0 = 0; k0 < 1024; k0 += 64) {
        __syncthreads();
#pragma unroll
        for (int i = 0; i < 4; ++i) {
            int rb = wid * 32 + i * 8;
            gload_lds16(A + (size_t)(row0 + rb + lr) * 1024 + k0 + lc, As + rb * 64);
            gload_lds16(B + (size_t)(col0 + rb + lr) * 1024 + k0 + lc, Bs + rb * 64);
        }
        __syncthreads();
#pragma unroll
        for (int ks = 0; ks < 2; ++ks) {
            bf16x8 a[4], b[4];
            int ko = ks * 32 + kgr;
#pragma unroll
            for (int mi = 0; mi < 4; ++mi)
                a[mi] = *(const bf16x8*)(As + (wr + mi * 16 + rsel) * 64 + ko);
#pragma unroll
            for (int nj = 0; nj < 4; ++nj)
                b[nj] = *(const bf16x8*)(Bs + (wc + nj * 16 + rsel) * 64 + ko);
#pragma unroll
            for (int mi = 0; mi < 4; ++mi)
#pragma unroll
                for (int nj = 0; nj < 4; ++nj)
                    acc[mi][nj] = mfma16(a[mi], b[nj], acc[mi][nj]);
        }
    }
    const int rbase = row0 + wr + ((lane >> 4) << 2);
    const int cbase = col0 + wc + rsel;
#pragma unroll
    for (int mi = 0; mi < 4; ++mi)
#pragma unroll
        for (int nj = 0; nj < 4; ++nj)
#pragma unroll
            for (int r = 0; r < 4; ++r)
                C[(size_t)(rbase + mi * 16 + r) * 3072 + cbase + nj * 16] =
                    f2bf(acc[mi][nj][r]);
}

// ---------------------------------------------------------------------------
// Build Vt[bh][64][2048] from qkv V-section via LDS transpose
// ---------------------------------------------------------------------------
__global__ __launch_bounds__(256) void k_vt(
    const unsigned short* __restrict__ qkv, unsigned short* __restrict__ Vt)
{
    __shared__ unsigned short T[64][72];   // [n][dv]
    const int tid = threadIdx.x, lane = tid & 63, wid = tid >> 6;
    const int bh = blockIdx.y, b = bh >> 4, h = bh & 15;
    const int n0 = blockIdx.x * 64;
    const unsigned short* src = qkv + (size_t)(b * 2048 + n0) * 3072 + 2048 + h * 64;
#pragma unroll
    for (int j = 0; j < 2; ++j) {
        int idx = tid + j * 256;
        int n = idx >> 3, c8 = (idx & 7) << 3;
        *(bf16x8*)&T[n][c8] = *(const bf16x8*)(src + (size_t)n * 3072 + c8);
    }
    __syncthreads();
#pragma unroll
    for (int i = 0; i < 16; ++i) {
        int dv = wid * 16 + i;
        Vt[((size_t)bh * 64 + dv) * 2048 + n0 + lane] = T[lane][dv];
    }
}

// ---------------------------------------------------------------------------
// vsum[bh*64+dv] = sum_n V[bh][n][dv]   (read Vt rows, contiguous)
// ---------------------------------------------------------------------------
__global__ __launch_bounds__(256) void k_vsum(
    const unsigned short* __restrict__ Vt, float* __restrict__ vsum)
{
    int wid = threadIdx.x >> 6, lane = threadIdx.x & 63;
    int row = blockIdx.x * 4 + wid;            // 0..2047
    float s = 0.f;
#pragma unroll
    for (int it = 0; it < 4; ++it) {
        bf16x8 v = *(const bf16x8*)(Vt + (size_t)row * 2048 + it * 512 + lane * 8);
#pragma unroll
        for (int i = 0; i < 8; ++i) s += bf2f((unsigned short)v[i]);
    }
#pragma unroll
    for (int m = 32; m; m >>= 1) s += __shfl_xor(s, m);
    if (lane == 0) vsum[row] = s;
}

// ---------------------------------------------------------------------------
// Flash attention, 32x32x16 MFMA, P entirely in registers (permlane32_swap).
// 128-thread blocks (2 waves x 32 q-rows), q-tile 64, grid 1024, XCD swizzle.
// exp2-only softmax; l = scalar accumulation (col=lane&31 is lane-local).
// K/V double-buffered via gload_lds with XOR slot swizzle; per-tile vmcnt+bar.
// ---------------------------------------------------------------------------
__global__ __launch_bounds__(128) void k_attn(
    const unsigned short* __restrict__ qkv, const unsigned short* __restrict__ Vt,
    const float* __restrict__ vsum,
    const float* __restrict__ alpha_p, const float* __restrict__ beta_p,
    const float* __restrict__ gamma_p,
    unsigned short* __restrict__ AO)
{
    __shared__ unsigned short Ks[2][64][64];   // [key][hd], swizzled slots
    __shared__ unsigned short Vs[2][64][64];   // [dv][key], swizzled slots
    const int tid = threadIdx.x, lane = tid & 63, wid = tid >> 6;
    // bijective XCD swizzle: nwg=1024, 128 consecutive logical blocks per XCD
    const int swz = (blockIdx.x & 7) * 128 + (blockIdx.x >> 3);
    const int bh = swz >> 5, qtb = swz & 31;
    const int b = bh >> 4, h = bh & 15;
    const int q0 = qtb * 64;
    const int l31 = lane & 31, hi = lane >> 5, l7 = lane & 7;
    const int qrow = q0 + wid * 32 + l31;

    // Q B-fragments (col=q=lane&31, k_hd=hi*8+e per 16-slice), pre-scaled
    const float QSC = 1.4426950408889634f / 32.0f;
    bf16x8 qb[4];
    {
        const unsigned short* qptr = qkv + (size_t)(b * 2048 + qrow) * 3072 + h * 64;
#pragma unroll
        for (int ks = 0; ks < 4; ++ks) {
            bf16x8 qv = *(const bf16x8*)(qptr + ks * 16 + hi * 8);
#pragma unroll
            for (int e = 0; e < 8; ++e)
                qb[ks][e] = (short)f2bf(bf2f((unsigned short)qv[e]) * QSC);
        }
    }

    const unsigned short* Kg = qkv + (size_t)(b * 2048) * 3072 + 1024 + h * 64;
    const unsigned short* Vg = Vt + (size_t)bh * 64 * 2048;
    const int sr = lane >> 3;                 // 0..7 within 8-row slab
    const int ss = (lane & 7) ^ sr;           // inverse-swizzled source slot

#define STAGE(KT, BUF)                                                         \
    {                                                                          \
        int _k0 = (KT) * 64;                                                   \
        _Pragma("unroll")                                                      \
        for (int j = 0; j < 4; ++j) {                                          \
            int rb = j * 16 + wid * 8;                                         \
            gload_lds16(Kg + (size_t)(_k0 + rb + sr) * 3072 + ss * 8,          \
                        &Ks[BUF][rb][0]);                                      \
            gload_lds16(Vg + (size_t)(rb + sr) * 2048 + _k0 + ss * 8,          \
                        &Vs[BUF][rb][0]);                                      \
        }                                                                      \
    }

    f32x16 o[2];
    o[0] = (f32x16)0.f; o[1] = (f32x16)0.f;
    float lsum = 0.f;

    STAGE(0, 0);
    asm volatile("s_waitcnt vmcnt(0)" ::: "memory");
    __syncthreads();

    for (int kt = 0; kt < 32; ++kt) {
        const int cur = kt & 1;
        if (kt < 31) STAGE(kt + 1, cur ^ 1);   // prefetch next tile (in flight)

        // QK^T swapped: s[t] = S^T[key = t*32 + (r+8j+4hi)][q = l31]
        f32x16 s[2];
        s[0] = (f32x16)0.f; s[1] = (f32x16)0.f;
        __builtin_amdgcn_s_setprio(1);
#pragma unroll
        for (int t = 0; t < 2; ++t)
#pragma unroll
            for (int ks = 0; ks < 4; ++ks) {
                bf16x8 ak = *(const bf16x8*)(
                    &Ks[cur][t * 32 + l31][(((ks << 1) | hi) ^ l7) * 8]);
                s[t] = mfma32(ak, qb[ks], s[t]);
            }
        __builtin_amdgcn_s_setprio(0);

        // P = exp2(s): pack quad words, accumulate l (all lane-local, col=q)
        unsigned w0[2][4], w1[2][4];
#pragma unroll
        for (int t = 0; t < 2; ++t)
#pragma unroll
            for (int j = 0; j < 4; ++j) {
                float p0 = exp2f(s[t][4 * j + 0]);
                float p1 = exp2f(s[t][4 * j + 1]);
                float p2 = exp2f(s[t][4 * j + 2]);
                float p3 = exp2f(s[t][4 * j + 3]);
                lsum += (p0 + p1) + (p2 + p3);
                union { __hip_bfloat162 h2; unsigned u; } pk0, pk1;
                pk0.h2 = __float22bfloat162_rn(make_float2(p0, p1));
                pk1.h2 = __float22bfloat162_rn(make_float2(p2, p3));
                w0[t][j] = pk0.u; w1[t][j] = pk1.u;
            }
        // B-fragments for PV via permlane32_swap (frag ks: quads 2ks,2ks+1)
        bf16x8 pb[4];
#pragma unroll
        for (int ks = 0; ks < 4; ++ks) {
            const int t = ks >> 1, jj = (ks & 1) * 2;
            unsigned A = w0[t][jj], B = w0[t][jj + 1];
            unsigned C = w1[t][jj], D = w1[t][jj + 1];
            asm volatile("v_permlane32_swap_b32 %0, %1" : "+v"(A), "+v"(B));
            asm volatile("v_permlane32_swap_b32 %0, %1" : "+v"(C), "+v"(D));
            union { unsigned u[4]; bf16x8 v; } f;
            f.u[0] = A; f.u[1] = C; f.u[2] = B; f.u[3] = D;
            pb[ks] = f.v;
        }

        // PV: o[t] = O^T[dv = t*32 + (r+8j+4hi)][q = l31]
        __builtin_amdgcn_s_setprio(1);
#pragma unroll
        for (int t = 0; t < 2; ++t)
#pragma unroll
            for (int ks = 0; ks < 4; ++ks) {
                bf16x8 av = *(const bf16x8*)(
                    &Vs[cur][t * 32 + l31][(((ks << 1) | hi) ^ l7) * 8]);
                o[t] = mfma32(av, pb[ks], o[t]);
            }
        __builtin_amdgcn_s_setprio(0);

        asm volatile("s_waitcnt vmcnt(0)" ::: "memory");  // next tile landed
        __syncthreads();
    }

    const float ltot = lsum + __shfl_xor(lsum, 32);

    // epilogue: beta*softmax + alpha*V[q] - gamma/n * vsum   (q lane-local)
    const float alpha = *alpha_p, beta = *beta_p;
    const float gn = (*gamma_p) / 2048.0f;
    const float linv = beta / ltot;
    const unsigned short* vrow = qkv + (size_t)(b * 2048 + qrow) * 3072 + 2048 + h * 64;
    unsigned short* arow = AO + (size_t)(b * 2048 + qrow) * 1024 + h * 64;
#pragma unroll
    for (int t = 0; t < 2; ++t)
#pragma unroll
        for (int j = 0; j < 4; ++j) {
            const int dv0 = t * 32 + 8 * j + 4 * hi;
            bf16x4 vd = *(const bf16x4*)(vrow + dv0);
            f32x4 vs = *(const f32x4*)(vsum + bh * 64 + dv0);
            bf16x4 outp;
#pragma unroll
            for (int r = 0; r < 4; ++r) {
                float res = o[t][4 * j + r] * linv
                          + alpha * bf2f((unsigned short)vd[r]) - gn * vs[r];
                outp[r] = (short)f2bf(res);
            }
            *(bf16x4*)(arow + dv0) = outp;
        }
#undef STAGE
}

// ---------------------------------------------------------------------------
// GEMM2: out f32[4096][1024] = AO bf16 @ Wt2^T + bias
// ---------------------------------------------------------------------------
__global__ __launch_bounds__(256) void k_gemm2(
    const unsigned short* __restrict__ A, const unsigned short* __restrict__ B,
    const float* __restrict__ bias, float* __restrict__ Out)
{
    __shared__ unsigned short As[128 * 64];
    __shared__ unsigned short Bs[128 * 64];
    const int tid = threadIdx.x, lane = tid & 63, wid = tid >> 6;
    const int wr = (wid >> 1) * 64, wc = (wid & 1) * 64;
    const int row0 = blockIdx.y * 128, col0 = blockIdx.x * 128;
    const int rsel = lane & 15, kgr = (lane >> 4) * 8;
    const int lr = lane >> 3, lc = (lane & 7) * 8;

    f32x4 acc[4][4];
#pragma unroll
    for (int i = 0; i < 4; ++i)
#pragma unroll
        for (int j = 0; j < 4; ++j) acc[i][j] = (f32x4){0.f, 0.f, 0.f, 0.f};

    for (int k0 = 0; k0 < 1024; k0 += 64) {
        __syncthreads();
#pragma unroll
        for (int i = 0; i < 4; ++i) {
            int rb = wid * 32 + i * 8;
            gload_lds16(A + (size_t)(row0 + rb + lr) * 1024 + k0 + lc, As + rb * 64);
            gload_lds16(B + (size_t)(col0 + rb + lr) * 1024 + k0 + lc, Bs + rb * 64);
        }
        __syncthreads();
#pragma unroll
        for (int ks = 0; ks < 2; ++ks) {
            bf16x8 a[4], b[4];
            int ko = ks * 32 + kgr;
#pragma unroll
            for (int mi = 0; mi < 4; ++mi)
                a[mi] = *(const bf16x8*)(As + (wr + mi * 16 + rsel) * 64 + ko);
#pragma unroll
            for (int nj = 0; nj < 4; ++nj)
                b[nj] = *(const bf16x8*)(Bs + (wc + nj * 16 + rsel) * 64 + ko);
#pragma unroll
            for (int mi = 0; mi < 4; ++mi)
#pragma unroll
                for (int nj = 0; nj < 4; ++nj)
                    acc[mi][nj] = mfma16(a[mi], b[nj], acc[mi][nj]);
        }
    }
    const int rbase = row0 + wr + ((lane >> 4) << 2);
    const int cbase = col0 + wc + rsel;
#pragma unroll
    for (int mi = 0; mi < 4; ++mi)
#pragma unroll
        for (int nj = 0; nj < 4; ++nj) {
            int gc = cbase + nj * 16;
            float bv = bias[gc];
#pragma unroll
            for (int r = 0; r < 4; ++r)
                Out[(size_t)(rbase + mi * 16 + r) * 1024 + gc] = acc[mi][nj][r] + bv;
        }
}

// ---------------------------------------------------------------------------
extern "C" void kernel_launch(void* const* d_in, const int* in_sizes, int n_in,
                              void* d_out, int out_size, void* d_ws, size_t ws_size,
                              hipStream_t stream) {
    const float* x     = (const float*)d_in[0];
    const float* Wqkv  = (const float*)d_in[1];
    const float* Wout  = (const float*)d_in[2];
    const float* bout  = (const float*)d_in[3];
    const float* alpha = (const float*)d_in[4];
    const float* beta  = (const float*)d_in[5];
    const float* gamma = (const float*)d_in[6];
    float* out = (float*)d_out;

    char* ws = (char*)d_ws;
    unsigned short* Xb  = (unsigned short*)(ws);               // 8 MB (reused as AO)
    unsigned short* Wt1 = (unsigned short*)(ws + 8388608);     // 6 MB
    unsigned short* Wt2 = (unsigned short*)(ws + 14680064);    // 2 MB
    unsigned short* qkv = (unsigned short*)(ws + 16777216);    // 24 MB
    unsigned short* Vt  = (unsigned short*)(ws + 41943040);    // 8 MB
    float* vsum         = (float*)(ws + 50331648);             // 8 KB
    unsigned short* AO  = Xb;   // Xb dead after k_gemm1

    k_cvt<<<1024, 256, 0, stream>>>(x, Xb);
    k_wt<<<dim3(48, 16), 256, 0, stream>>>(Wqkv, Wt1, 3072);
    k_wt<<<dim3(16, 16), 256, 0, stream>>>(Wout, Wt2, 1024);
    k_gemm1<<<dim3(24, 32), 256, 0, stream>>>(Xb, Wt1, qkv);
    k_vt<<<dim3(32, 32), 256, 0, stream>>>(qkv, Vt);
    k_vsum<<<512, 256, 0, stream>>>(Vt, vsum);
    k_attn<<<1024, 128, 0, stream>>>(qkv, Vt, vsum, alpha, beta, gamma, AO);
    k_gemm2<<<dim3(8, 32), 256, 0, stream>>>(AO, Wt2, bout, out);
}

// Round 9
// 152.861 us; speedup vs baseline: 1.1662x; 1.1662x over previous
//
#include <hip/hip_runtime.h>
#include <hip/hip_bf16.h>

#define DEVI __device__ __forceinline__

typedef __attribute__((ext_vector_type(8))) short bf16x8;
typedef __attribute__((ext_vector_type(4))) short bf16x4;
typedef __attribute__((ext_vector_type(4))) float f32x4;

DEVI unsigned short f2bf(float f) {
    unsigned u = __float_as_uint(f);
    u += 0x7FFF + ((u >> 16) & 1);
    return (unsigned short)(u >> 16);
}
DEVI float bf2f(unsigned short h) {
    return __uint_as_float(((unsigned)h) << 16);
}
DEVI f32x4 mfma16(bf16x8 a, bf16x8 b, f32x4 c) {
    return __builtin_amdgcn_mfma_f32_16x16x32_bf16(a, b, c, 0, 0, 0);
}
DEVI void gload_lds16(const void* g, void* l) {
    __builtin_amdgcn_global_load_lds(
        (const __attribute__((address_space(1))) unsigned int*)g,
        (__attribute__((address_space(3))) unsigned int*)l, 16, 0, 0);
}

// ---------------------------------------------------------------------------
// Fused prep: blocks [0,1024) convert X f32->bf16; [1024,1792) transpose
// W_qkv (Q-columns pre-scaled by log2(e)/32); [1792,2048) transpose W_out.
// ---------------------------------------------------------------------------
DEVI void wt_body(const float* __restrict__ W, unsigned short* __restrict__ Wt,
                  int N, int n0, int k0, float sc, int tid,
                  unsigned short (*T)[72])
{
#pragma unroll
    for (int j = 0; j < 4; ++j) {
        int idx = tid + j * 256;
        int kk = idx >> 4, c4 = (idx & 15) << 2;
        float4 v = *(const float4*)(W + (size_t)(k0 + kk) * N + n0 + c4);
        T[c4 + 0][kk] = f2bf(v.x * sc); T[c4 + 1][kk] = f2bf(v.y * sc);
        T[c4 + 2][kk] = f2bf(v.z * sc); T[c4 + 3][kk] = f2bf(v.w * sc);
    }
    __syncthreads();
#pragma unroll
    for (int j = 0; j < 4; ++j) {
        int idx = tid + j * 256;
        int n = idx >> 4, c4 = (idx & 15) << 2;
        *(bf16x4*)(Wt + (size_t)(n0 + n) * 1024 + k0 + c4) = *(bf16x4*)&T[n][c4];
    }
}

__global__ __launch_bounds__(256) void k_prep(
    const float* __restrict__ X, const float* __restrict__ Wqkv,
    const float* __restrict__ Wout,
    unsigned short* __restrict__ Xb, unsigned short* __restrict__ Wt1,
    unsigned short* __restrict__ Wt2)
{
    __shared__ unsigned short T[64][72];
    const int tid = threadIdx.x;
    const int bid = blockIdx.x;
    const float QSC = 1.4426950408889634f / 32.0f;
    if (bid < 1024) {
        int i = bid * 256 + tid;
#pragma unroll
        for (int j = 0; j < 4; ++j) {
            int idx = i + j * 262144;
            float4 v = *(const float4*)(X + (size_t)idx * 4);
            bf16x4 hv;
            hv[0] = (short)f2bf(v.x); hv[1] = (short)f2bf(v.y);
            hv[2] = (short)f2bf(v.z); hv[3] = (short)f2bf(v.w);
            *(bf16x4*)(Xb + (size_t)idx * 4) = hv;
        }
    } else if (bid < 1792) {
        int idx = bid - 1024;
        int n0 = (idx % 48) * 64, k0 = (idx / 48) * 64;
        wt_body(Wqkv, Wt1, 3072, n0, k0, (n0 < 1024) ? QSC : 1.0f, tid, T);
    } else {
        int idx = bid - 1792;
        int n0 = (idx & 15) * 64, k0 = (idx >> 4) * 64;
        wt_body(Wout, Wt2, 1024, n0, k0, 1.0f, tid, T);
    }
}

// ---------------------------------------------------------------------------
// GEMM1: qkv[4096][3072] bf16 = Xb[4096][1024] @ Wt1^T   (B^T layout, m97-style)
// ---------------------------------------------------------------------------
__global__ __launch_bounds__(256) void k_gemm1(
    const unsigned short* __restrict__ A, const unsigned short* __restrict__ B,
    unsigned short* __restrict__ C)
{
    __shared__ unsigned short As[128 * 64];
    __shared__ unsigned short Bs[128 * 64];
    const int tid = threadIdx.x, lane = tid & 63, wid = tid >> 6;
    const int wr = (wid >> 1) * 64, wc = (wid & 1) * 64;
    const int row0 = blockIdx.y * 128, col0 = blockIdx.x * 128;
    const int rsel = lane & 15, kgr = (lane >> 4) * 8;
    const int lr = lane >> 3, lc = (lane & 7) * 8;

    f32x4 acc[4][4];
#pragma unroll
    for (int i = 0; i < 4; ++i)
#pragma unroll
        for (int j = 0; j < 4; ++j) acc[i][j] = (f32x4){0.f, 0.f, 0.f, 0.f};

    for (int k0 = 0; k0 < 1024; k0 += 64) {
        __syncthreads();
#pragma unroll
        for (int i = 0; i < 4; ++i) {
            int rb = wid * 32 + i * 8;
            gload_lds16(A + (size_t)(row0 + rb + lr) * 1024 + k0 + lc, As + rb * 64);
            gload_lds16(B + (size_t)(col0 + rb + lr) * 1024 + k0 + lc, Bs + rb * 64);
        }
        __syncthreads();
#pragma unroll
        for (int ks = 0; ks < 2; ++ks) {
            bf16x8 a[4], b[4];
            int ko = ks * 32 + kgr;
#pragma unroll
            for (int mi = 0; mi < 4; ++mi)
                a[mi] = *(const bf16x8*)(As + (wr + mi * 16 + rsel) * 64 + ko);
#pragma unroll
            for (int nj = 0; nj < 4; ++nj)
                b[nj] = *(const bf16x8*)(Bs + (wc + nj * 16 + rsel) * 64 + ko);
#pragma unroll
            for (int mi = 0; mi < 4; ++mi)
#pragma unroll
                for (int nj = 0; nj < 4; ++nj)
                    acc[mi][nj] = mfma16(a[mi], b[nj], acc[mi][nj]);
        }
    }
    const int rbase = row0 + wr + ((lane >> 4) << 2);
    const int cbase = col0 + wc + rsel;
#pragma unroll
    for (int mi = 0; mi < 4; ++mi)
#pragma unroll
        for (int nj = 0; nj < 4; ++nj)
#pragma unroll
            for (int r = 0; r < 4; ++r)
                C[(size_t)(rbase + mi * 16 + r) * 3072 + cbase + nj * 16] =
                    f2bf(acc[mi][nj][r]);
}

// ---------------------------------------------------------------------------
// Build Vt[bh][64][2048] from qkv V-section via LDS transpose; fused vsum
// partial column-sums (atomicAdd; vsum zeroed by host-side memsetAsync).
// ---------------------------------------------------------------------------
__global__ __launch_bounds__(256) void k_vt(
    const unsigned short* __restrict__ qkv, unsigned short* __restrict__ Vt,
    float* __restrict__ vsum)
{
    __shared__ unsigned short T[64][72];   // [n][dv]
    __shared__ float ps[64];
    const int tid = threadIdx.x, lane = tid & 63, wid = tid >> 6;
    const int bh = blockIdx.y, b = bh >> 4, h = bh & 15;
    const int n0 = blockIdx.x * 64;
    const unsigned short* src = qkv + (size_t)(b * 2048 + n0) * 3072 + 2048 + h * 64;
#pragma unroll
    for (int j = 0; j < 2; ++j) {
        int idx = tid + j * 256;
        int n = idx >> 3, c8 = (idx & 7) << 3;
        *(bf16x8*)&T[n][c8] = *(const bf16x8*)(src + (size_t)n * 3072 + c8);
    }
    if (tid < 64) ps[tid] = 0.f;
    __syncthreads();
#pragma unroll
    for (int i = 0; i < 16; ++i) {
        int dv = wid * 16 + i;
        Vt[((size_t)bh * 64 + dv) * 2048 + n0 + lane] = T[lane][dv];
    }
    // partial column sums: thread sums 16 n-rows of its dv column
    {
        const int col = tid & 63, qtr = tid >> 6;
        float s = 0.f;
#pragma unroll
        for (int i = 0; i < 16; ++i) s += bf2f(T[qtr * 16 + i][col]);
        atomicAdd(&ps[col], s);
        __syncthreads();
        if (tid < 64) atomicAdd(&vsum[bh * 64 + tid], ps[tid]);
    }
}

// ---------------------------------------------------------------------------
// Flash attention, q-tile 64, grid 1024 (XCD-swizzled), exp2-only softmax.
// R7 structure (proven fastest) + raw v_exp_f32 (builtin), pre-scaled Q from
// prep, incremental staging pointers, 2x-unrolled loop (const LDS buffers).
// ---------------------------------------------------------------------------
__global__ __launch_bounds__(256) void k_attn(
    const unsigned short* __restrict__ qkv, const unsigned short* __restrict__ Vt,
    const float* __restrict__ vsum,
    const float* __restrict__ alpha_p, const float* __restrict__ beta_p,
    const float* __restrict__ gamma_p,
    unsigned short* __restrict__ AO)
{
    __shared__ unsigned short Ks[2][64][64];   // linear, swizzled content
    __shared__ unsigned short Vs[2][64][64];   // linear, swizzled content
    __shared__ unsigned short Ps[4][16][64];   // per-wave, 16B-slot XOR swizzle
    const int tid = threadIdx.x, lane = tid & 63, wid = tid >> 6;
    // bijective XCD swizzle: nwg=1024, 128 consecutive logical blocks per XCD
    const int swz = (blockIdx.x & 7) * 128 + (blockIdx.x >> 3);
    const int bh = swz >> 5, qtb = swz & 31;
    const int b = bh >> 4, h = bh & 15;
    const int q0 = qtb * 64;
    const int rsel = lane & 15, g = lane >> 4;
    const int g4 = g << 2;
    const int wq0 = wid * 16;
    const int r7 = rsel & 7;

    // Q fragments in registers (already pre-scaled by log2(e)/32 in prep)
    bf16x8 bq[2];
    {
        const unsigned short* qrow =
            qkv + (size_t)(b * 2048 + q0 + wq0 + rsel) * 3072 + h * 64;
        bq[0] = *(const bf16x8*)(qrow + g * 8);
        bq[1] = *(const bf16x8*)(qrow + 32 + g * 8);
    }

    // incremental staging pointers (inverse-swizzled source slots)
    const int sr = lane >> 3;                 // 0..7 within 8-row slab
    const int ss = (lane & 7) ^ sr;           // 16B slot in global row
    const int rb0 = wid * 16, rb1 = wid * 16 + 8;
    const unsigned short* kp0 = qkv + (size_t)(b * 2048) * 3072 + 1024 + h * 64
                              + (size_t)(rb0 + sr) * 3072 + ss * 8;
    const unsigned short* kp1 = kp0 + (size_t)8 * 3072;
    const unsigned short* vp0 = Vt + (size_t)bh * 64 * 2048
                              + (size_t)(rb0 + sr) * 2048 + ss * 8;
    const unsigned short* vp1 = vp0 + (size_t)8 * 2048;
    const size_t KADV = (size_t)64 * 3072;

    f32x4 o[4], ol;
#pragma unroll
    for (int dj = 0; dj < 4; ++dj) o[dj] = (f32x4){0.f, 0.f, 0.f, 0.f};
    ol = (f32x4){0.f, 0.f, 0.f, 0.f};
    bf16x8 ones;
#pragma unroll
    for (int e = 0; e < 8; ++e) ones[e] = (short)0x3F80;   // bf16 1.0

    // prologue: stage tile 0 into buf 0
    gload_lds16(kp0, &Ks[0][rb0][0]); gload_lds16(kp1, &Ks[0][rb1][0]);
    gload_lds16(vp0, &Vs[0][rb0][0]); gload_lds16(vp1, &Vs[0][rb1][0]);
    kp0 += KADV; kp1 += KADV; vp0 += 64; vp1 += 64;
    asm volatile("s_waitcnt vmcnt(0)" ::: "memory");
    __syncthreads();

#define BODY(CUR, NXT, DOPF)                                                   \
    {                                                                          \
        if (DOPF) {                                                            \
            gload_lds16(kp0, &Ks[NXT][rb0][0]);                                \
            gload_lds16(kp1, &Ks[NXT][rb1][0]);                                \
            gload_lds16(vp0, &Vs[NXT][rb0][0]);                                \
            gload_lds16(vp1, &Vs[NXT][rb1][0]);                                \
            kp0 += KADV; kp1 += KADV; vp0 += 64; vp1 += 64;                    \
        }                                                                      \
        f32x4 s[4];                                                            \
        _Pragma("unroll")                                                      \
        for (int kj = 0; kj < 4; ++kj) s[kj] = (f32x4){0.f, 0.f, 0.f, 0.f};    \
        __builtin_amdgcn_s_setprio(1);                                         \
        _Pragma("unroll")                                                      \
        for (int ks = 0; ks < 2; ++ks) {                                       \
            const int sl = ((ks * 4 + g) ^ r7) * 8;                            \
            bf16x8 ak[4];                                                      \
            _Pragma("unroll")                                                  \
            for (int kj = 0; kj < 4; ++kj)                                     \
                ak[kj] = *(const bf16x8*)(&Ks[CUR][kj * 16 + rsel][sl]);       \
            _Pragma("unroll")                                                  \
            for (int kj = 0; kj < 4; ++kj)                                     \
                s[kj] = mfma16(ak[kj], bq[ks], s[kj]);                         \
        }                                                                      \
        __builtin_amdgcn_s_setprio(0);                                         \
        _Pragma("unroll")                                                      \
        for (int kj = 0; kj < 4; ++kj) {                                       \
            float p0 = __builtin_amdgcn_exp2f(s[kj][0]);                       \
            float p1 = __builtin_amdgcn_exp2f(s[kj][1]);                       \
            float p2 = __builtin_amdgcn_exp2f(s[kj][2]);                       \
            float p3 = __builtin_amdgcn_exp2f(s[kj][3]);                       \
            union { __hip_bfloat162 h2[2]; uint2 u; } pk;                      \
            pk.h2[0] = __float22bfloat162_rn(make_float2(p0, p1));             \
            pk.h2[1] = __float22bfloat162_rn(make_float2(p2, p3));             \
            const int slot16 = (kj * 2 + (g >> 1)) ^ r7;                       \
            *(uint2*)(&Ps[wid][rsel][slot16 * 8 + (g & 1) * 4]) = pk.u;        \
        }                                                                      \
        __builtin_amdgcn_s_setprio(1);                                         \
        _Pragma("unroll")                                                      \
        for (int ks = 0; ks < 2; ++ks) {                                       \
            const int sl = ((ks * 4 + g) ^ r7) * 8;                            \
            bf16x8 pa = *(const bf16x8*)(&Ps[wid][rsel][sl]);                  \
            bf16x8 vb[4];                                                      \
            _Pragma("unroll")                                                  \
            for (int dj = 0; dj < 4; ++dj)                                     \
                vb[dj] = *(const bf16x8*)(&Vs[CUR][dj * 16 + rsel][sl]);       \
            _Pragma("unroll")                                                  \
            for (int dj = 0; dj < 4; ++dj)                                     \
                o[dj] = mfma16(pa, vb[dj], o[dj]);                             \
            ol = mfma16(pa, ones, ol);                                         \
        }                                                                      \
        __builtin_amdgcn_s_setprio(0);                                         \
        asm volatile("s_waitcnt vmcnt(0)" ::: "memory");                       \
        __syncthreads();                                                       \
    }

#pragma unroll 1
    for (int i = 0; i < 16; ++i) {
        BODY(0, 1, true);        // kt = 2i   (prefetch 2i+1, always valid)
        BODY(1, 0, (i < 15));    // kt = 2i+1 (prefetch 2i+2 unless last)
    }
#undef BODY

    // epilogue: beta*softmax + alpha*V[q] - gamma/n * vsum
    const float alpha = *alpha_p, beta = *beta_p;
    const float gn = (*gamma_p) / 2048.0f;
    float linv[4];
#pragma unroll
    for (int r = 0; r < 4; ++r)
        linv[r] = beta / ol[r];
#pragma unroll
    for (int dj = 0; dj < 4; ++dj)
#pragma unroll
        for (int r = 0; r < 4; ++r) {
            int qrow = q0 + wq0 + g4 + r;
            int dv = dj * 16 + rsel;
            float ov = o[dj][r] * linv[r];
            float vdiag = bf2f(qkv[(size_t)(b * 2048 + qrow) * 3072 + 2048 + h * 64 + dv]);
            float vs = vsum[bh * 64 + dv];
            float res = ov + alpha * vdiag - gn * vs;
            AO[(size_t)(b * 2048 + qrow) * 1024 + h * 64 + dv] = f2bf(res);
        }
}

// ---------------------------------------------------------------------------
// GEMM2: out f32[4096][1024] = AO bf16 @ Wt2^T + bias
// ---------------------------------------------------------------------------
__global__ __launch_bounds__(256) void k_gemm2(
    const unsigned short* __restrict__ A, const unsigned short* __restrict__ B,
    const float* __restrict__ bias, float* __restrict__ Out)
{
    __shared__ unsigned short As[128 * 64];
    __shared__ unsigned short Bs[128 * 64];
    const int tid = threadIdx.x, lane = tid & 63, wid = tid >> 6;
    const int wr = (wid >> 1) * 64, wc = (wid & 1) * 64;
    const int row0 = blockIdx.y * 128, col0 = blockIdx.x * 128;
    const int rsel = lane & 15, kgr = (lane >> 4) * 8;
    const int lr = lane >> 3, lc = (lane & 7) * 8;

    f32x4 acc[4][4];
#pragma unroll
    for (int i = 0; i < 4; ++i)
#pragma unroll
        for (int j = 0; j < 4; ++j) acc[i][j] = (f32x4){0.f, 0.f, 0.f, 0.f};

    for (int k0 = 0; k0 < 1024; k0 += 64) {
        __syncthreads();
#pragma unroll
        for (int i = 0; i < 4; ++i) {
            int rb = wid * 32 + i * 8;
            gload_lds16(A + (size_t)(row0 + rb + lr) * 1024 + k0 + lc, As + rb * 64);
            gload_lds16(B + (size_t)(col0 + rb + lr) * 1024 + k0 + lc, Bs + rb * 64);
        }
        __syncthreads();
#pragma unroll
        for (int ks = 0; ks < 2; ++ks) {
            bf16x8 a[4], b[4];
            int ko = ks * 32 + kgr;
#pragma unroll
            for (int mi = 0; mi < 4; ++mi)
                a[mi] = *(const bf16x8*)(As + (wr + mi * 16 + rsel) * 64 + ko);
#pragma unroll
            for (int nj = 0; nj < 4; ++nj)
                b[nj] = *(const bf16x8*)(Bs + (wc + nj * 16 + rsel) * 64 + ko);
#pragma unroll
            for (int mi = 0; mi < 4; ++mi)
#pragma unroll
                for (int nj = 0; nj < 4; ++nj)
                    acc[mi][nj] = mfma16(a[mi], b[nj], acc[mi][nj]);
        }
    }
    const int rbase = row0 + wr + ((lane >> 4) << 2);
    const int cbase = col0 + wc + rsel;
#pragma unroll
    for (int mi = 0; mi < 4; ++mi)
#pragma unroll
        for (int nj = 0; nj < 4; ++nj) {
            int gc = cbase + nj * 16;
            float bv = bias[gc];
#pragma unroll
            for (int r = 0; r < 4; ++r)
                Out[(size_t)(rbase + mi * 16 + r) * 1024 + gc] = acc[mi][nj][r] + bv;
        }
}

// ---------------------------------------------------------------------------
extern "C" void kernel_launch(void* const* d_in, const int* in_sizes, int n_in,
                              void* d_out, int out_size, void* d_ws, size_t ws_size,
                              hipStream_t stream) {
    const float* x     = (const float*)d_in[0];
    const float* Wqkv  = (const float*)d_in[1];
    const float* Wout  = (const float*)d_in[2];
    const float* bout  = (const float*)d_in[3];
    const float* alpha = (const float*)d_in[4];
    const float* beta  = (const float*)d_in[5];
    const float* gamma = (const float*)d_in[6];
    float* out = (float*)d_out;

    char* ws = (char*)d_ws;
    unsigned short* Xb  = (unsigned short*)(ws);               // 8 MB (reused as AO)
    unsigned short* Wt1 = (unsigned short*)(ws + 8388608);     // 6 MB
    unsigned short* Wt2 = (unsigned short*)(ws + 14680064);    // 2 MB
    unsigned short* qkv = (unsigned short*)(ws + 16777216);    // 24 MB
    unsigned short* Vt  = (unsigned short*)(ws + 41943040);    // 8 MB
    float* vsum         = (float*)(ws + 50331648);             // 8 KB
    unsigned short* AO  = Xb;   // Xb dead after k_gemm1

    hipMemsetAsync(vsum, 0, 2048 * sizeof(float), stream);
    k_prep<<<2048, 256, 0, stream>>>(x, Wqkv, Wout, Xb, Wt1, Wt2);
    k_gemm1<<<dim3(24, 32), 256, 0, stream>>>(Xb, Wt1, qkv);
    k_vt<<<dim3(32, 32), 256, 0, stream>>>(qkv, Vt, vsum);
    k_attn<<<1024, 256, 0, stream>>>(qkv, Vt, vsum, alpha, beta, gamma, AO);
    k_gemm2<<<dim3(8, 32), 256, 0, stream>>>(AO, Wt2, bout, out);
}

// Round 10
// 144.057 us; speedup vs baseline: 1.2374x; 1.0611x over previous
//
#include <hip/hip_runtime.h>
#include <hip/hip_bf16.h>

#define DEVI __device__ __forceinline__

typedef __attribute__((ext_vector_type(8))) short bf16x8;
typedef __attribute__((ext_vector_type(4))) short bf16x4;
typedef __attribute__((ext_vector_type(4))) float f32x4;

DEVI unsigned short f2bf(float f) {
    unsigned u = __float_as_uint(f);
    u += 0x7FFF + ((u >> 16) & 1);
    return (unsigned short)(u >> 16);
}
DEVI float bf2f(unsigned short h) {
    return __uint_as_float(((unsigned)h) << 16);
}
DEVI f32x4 mfma16(bf16x8 a, bf16x8 b, f32x4 c) {
    return __builtin_amdgcn_mfma_f32_16x16x32_bf16(a, b, c, 0, 0, 0);
}
DEVI void gload_lds16(const void* g, void* l) {
    __builtin_amdgcn_global_load_lds(
        (const __attribute__((address_space(1))) unsigned int*)g,
        (__attribute__((address_space(3))) unsigned int*)l, 16, 0, 0);
}

// ---------------------------------------------------------------------------
// Fused prep: blocks [0,1024) convert X f32->bf16; [1024,1792) transpose
// W_qkv (Q-columns pre-scaled by log2(e)/32); [1792,2048) transpose W_out.
// ---------------------------------------------------------------------------
DEVI void wt_body(const float* __restrict__ W, unsigned short* __restrict__ Wt,
                  int N, int n0, int k0, float sc, int tid,
                  unsigned short (*T)[72])
{
#pragma unroll
    for (int j = 0; j < 4; ++j) {
        int idx = tid + j * 256;
        int kk = idx >> 4, c4 = (idx & 15) << 2;
        float4 v = *(const float4*)(W + (size_t)(k0 + kk) * N + n0 + c4);
        T[c4 + 0][kk] = f2bf(v.x * sc); T[c4 + 1][kk] = f2bf(v.y * sc);
        T[c4 + 2][kk] = f2bf(v.z * sc); T[c4 + 3][kk] = f2bf(v.w * sc);
    }
    __syncthreads();
#pragma unroll
    for (int j = 0; j < 4; ++j) {
        int idx = tid + j * 256;
        int n = idx >> 4, c4 = (idx & 15) << 2;
        *(bf16x4*)(Wt + (size_t)(n0 + n) * 1024 + k0 + c4) = *(bf16x4*)&T[n][c4];
    }
}

__global__ __launch_bounds__(256) void k_prep(
    const float* __restrict__ X, const float* __restrict__ Wqkv,
    const float* __restrict__ Wout,
    unsigned short* __restrict__ Xb, unsigned short* __restrict__ Wt1,
    unsigned short* __restrict__ Wt2)
{
    __shared__ unsigned short T[64][72];
    const int tid = threadIdx.x;
    const int bid = blockIdx.x;
    const float QSC = 1.4426950408889634f / 32.0f;
    if (bid < 1024) {
        int i = bid * 256 + tid;
#pragma unroll
        for (int j = 0; j < 4; ++j) {
            int idx = i + j * 262144;
            float4 v = *(const float4*)(X + (size_t)idx * 4);
            bf16x4 hv;
            hv[0] = (short)f2bf(v.x); hv[1] = (short)f2bf(v.y);
            hv[2] = (short)f2bf(v.z); hv[3] = (short)f2bf(v.w);
            *(bf16x4*)(Xb + (size_t)idx * 4) = hv;
        }
    } else if (bid < 1792) {
        int idx = bid - 1024;
        int n0 = (idx % 48) * 64, k0 = (idx / 48) * 64;
        wt_body(Wqkv, Wt1, 3072, n0, k0, (n0 < 1024) ? QSC : 1.0f, tid, T);
    } else {
        int idx = bid - 1792;
        int n0 = (idx & 15) * 64, k0 = (idx >> 4) * 64;
        wt_body(Wout, Wt2, 1024, n0, k0, 1.0f, tid, T);
    }
}

// ---------------------------------------------------------------------------
// GEMM1: qkv[4096][3072] bf16 = Xb[4096][1024] @ Wt1^T   (B^T layout, m97-style)
// ---------------------------------------------------------------------------
__global__ __launch_bounds__(256) void k_gemm1(
    const unsigned short* __restrict__ A, const unsigned short* __restrict__ B,
    unsigned short* __restrict__ C)
{
    __shared__ unsigned short As[128 * 64];
    __shared__ unsigned short Bs[128 * 64];
    const int tid = threadIdx.x, lane = tid & 63, wid = tid >> 6;
    const int wr = (wid >> 1) * 64, wc = (wid & 1) * 64;
    const int row0 = blockIdx.y * 128, col0 = blockIdx.x * 128;
    const int rsel = lane & 15, kgr = (lane >> 4) * 8;
    const int lr = lane >> 3, lc = (lane & 7) * 8;

    f32x4 acc[4][4];
#pragma unroll
    for (int i = 0; i < 4; ++i)
#pragma unroll
        for (int j = 0; j < 4; ++j) acc[i][j] = (f32x4){0.f, 0.f, 0.f, 0.f};

    for (int k0 = 0; k0 < 1024; k0 += 64) {
        __syncthreads();
#pragma unroll
        for (int i = 0; i < 4; ++i) {
            int rb = wid * 32 + i * 8;
            gload_lds16(A + (size_t)(row0 + rb + lr) * 1024 + k0 + lc, As + rb * 64);
            gload_lds16(B + (size_t)(col0 + rb + lr) * 1024 + k0 + lc, Bs + rb * 64);
        }
        __syncthreads();
#pragma unroll
        for (int ks = 0; ks < 2; ++ks) {
            bf16x8 a[4], b[4];
            int ko = ks * 32 + kgr;
#pragma unroll
            for (int mi = 0; mi < 4; ++mi)
                a[mi] = *(const bf16x8*)(As + (wr + mi * 16 + rsel) * 64 + ko);
#pragma unroll
            for (int nj = 0; nj < 4; ++nj)
                b[nj] = *(const bf16x8*)(Bs + (wc + nj * 16 + rsel) * 64 + ko);
#pragma unroll
            for (int mi = 0; mi < 4; ++mi)
#pragma unroll
                for (int nj = 0; nj < 4; ++nj)
                    acc[mi][nj] = mfma16(a[mi], b[nj], acc[mi][nj]);
        }
    }
    const int rbase = row0 + wr + ((lane >> 4) << 2);
    const int cbase = col0 + wc + rsel;
#pragma unroll
    for (int mi = 0; mi < 4; ++mi)
#pragma unroll
        for (int nj = 0; nj < 4; ++nj)
#pragma unroll
            for (int r = 0; r < 4; ++r)
                C[(size_t)(rbase + mi * 16 + r) * 3072 + cbase + nj * 16] =
                    f2bf(acc[mi][nj][r]);
}

// ---------------------------------------------------------------------------
// Build Vt[bh][64][2048] from qkv V-section via LDS transpose; fused vsum
// partial column-sums (atomicAdd; vsum zeroed by host-side memsetAsync).
// ---------------------------------------------------------------------------
__global__ __launch_bounds__(256) void k_vt(
    const unsigned short* __restrict__ qkv, unsigned short* __restrict__ Vt,
    float* __restrict__ vsum)
{
    __shared__ unsigned short T[64][72];   // [n][dv]
    __shared__ float ps[64];
    const int tid = threadIdx.x, lane = tid & 63, wid = tid >> 6;
    const int bh = blockIdx.y, b = bh >> 4, h = bh & 15;
    const int n0 = blockIdx.x * 64;
    const unsigned short* src = qkv + (size_t)(b * 2048 + n0) * 3072 + 2048 + h * 64;
#pragma unroll
    for (int j = 0; j < 2; ++j) {
        int idx = tid + j * 256;
        int n = idx >> 3, c8 = (idx & 7) << 3;
        *(bf16x8*)&T[n][c8] = *(const bf16x8*)(src + (size_t)n * 3072 + c8);
    }
    if (tid < 64) ps[tid] = 0.f;
    __syncthreads();
#pragma unroll
    for (int i = 0; i < 16; ++i) {
        int dv = wid * 16 + i;
        Vt[((size_t)bh * 64 + dv) * 2048 + n0 + lane] = T[lane][dv];
    }
    {
        const int col = tid & 63, qtr = tid >> 6;
        float s = 0.f;
#pragma unroll
        for (int i = 0; i < 16; ++i) s += bf2f(T[qtr * 16 + i][col]);
        atomicAdd(&ps[col], s);
        __syncthreads();
        if (tid < 64) atomicAdd(&vsum[bh * 64 + tid], ps[tid]);
    }
}

// ---------------------------------------------------------------------------
// Flash attention, q-tile 128 (nq=2: 32 q-rows/wave), grid 512, XCD swizzle.
// exp2-only softmax (raw v_exp_f32), pre-scaled Q, dbuf gload_lds staging,
// XOR-swizzled LDS, setprio. nq=2 cuts LDS-read bytes per MFMA by 43%
// (K/V tile reads amortize over 2x q-work) -- LDS pipe was ~62% busy at nq=1.
// ---------------------------------------------------------------------------
__global__ __launch_bounds__(256) void k_attn(
    const unsigned short* __restrict__ qkv, const unsigned short* __restrict__ Vt,
    const float* __restrict__ vsum,
    const float* __restrict__ alpha_p, const float* __restrict__ beta_p,
    const float* __restrict__ gamma_p,
    unsigned short* __restrict__ AO)
{
    __shared__ unsigned short Ks[2][64][64];   // linear, swizzled content
    __shared__ unsigned short Vs[2][64][64];   // linear, swizzled content
    __shared__ unsigned short Ps[4][32][64];   // per-wave, 16B-slot XOR swizzle
    const int tid = threadIdx.x, lane = tid & 63, wid = tid >> 6;
    // bijective XCD swizzle: nwg=512, 64 consecutive logical blocks per XCD
    const int swz = (blockIdx.x & 7) * 64 + (blockIdx.x >> 3);
    const int bh = swz >> 4, qtb = swz & 15;
    const int b = bh >> 4, h = bh & 15;
    const int q0 = qtb * 128;
    const int rsel = lane & 15, g = lane >> 4;
    const int g4 = g << 2;
    const int wq0 = wid * 32;
    const int r7 = rsel & 7;

    // Q fragments in registers (already pre-scaled by log2(e)/32 in prep)
    bf16x8 bq[2][2];
#pragma unroll
    for (int qt = 0; qt < 2; ++qt) {
        const unsigned short* qrow =
            qkv + (size_t)(b * 2048 + q0 + wq0 + qt * 16 + rsel) * 3072 + h * 64;
        bq[qt][0] = *(const bf16x8*)(qrow + g * 8);
        bq[qt][1] = *(const bf16x8*)(qrow + 32 + g * 8);
    }

    // incremental staging pointers (inverse-swizzled source slots)
    const int sr = lane >> 3;                 // 0..7 within 8-row slab
    const int ss = (lane & 7) ^ sr;           // 16B slot in global row
    const int rb0 = wid * 16, rb1 = wid * 16 + 8;
    const unsigned short* kp0 = qkv + (size_t)(b * 2048) * 3072 + 1024 + h * 64
                              + (size_t)(rb0 + sr) * 3072 + ss * 8;
    const unsigned short* kp1 = kp0 + (size_t)8 * 3072;
    const unsigned short* vp0 = Vt + (size_t)bh * 64 * 2048
                              + (size_t)(rb0 + sr) * 2048 + ss * 8;
    const unsigned short* vp1 = vp0 + (size_t)8 * 2048;
    const size_t KADV = (size_t)64 * 3072;

    f32x4 o[2][4], ol[2];
#pragma unroll
    for (int qt = 0; qt < 2; ++qt) {
#pragma unroll
        for (int dj = 0; dj < 4; ++dj) o[qt][dj] = (f32x4){0.f, 0.f, 0.f, 0.f};
        ol[qt] = (f32x4){0.f, 0.f, 0.f, 0.f};
    }
    bf16x8 ones;
#pragma unroll
    for (int e = 0; e < 8; ++e) ones[e] = (short)0x3F80;   // bf16 1.0

    // prologue: stage tile 0 into buf 0
    gload_lds16(kp0, &Ks[0][rb0][0]); gload_lds16(kp1, &Ks[0][rb1][0]);
    gload_lds16(vp0, &Vs[0][rb0][0]); gload_lds16(vp1, &Vs[0][rb1][0]);
    kp0 += KADV; kp1 += KADV; vp0 += 64; vp1 += 64;
    asm volatile("s_waitcnt vmcnt(0)" ::: "memory");
    __syncthreads();

#define BODY(CUR, NXT, DOPF)                                                   \
    {                                                                          \
        if (DOPF) {                                                            \
            gload_lds16(kp0, &Ks[NXT][rb0][0]);                                \
            gload_lds16(kp1, &Ks[NXT][rb1][0]);                                \
            gload_lds16(vp0, &Vs[NXT][rb0][0]);                                \
            gload_lds16(vp1, &Vs[NXT][rb1][0]);                                \
            kp0 += KADV; kp1 += KADV; vp0 += 64; vp1 += 64;                    \
        }                                                                      \
        f32x4 s[2][4];                                                         \
        _Pragma("unroll")                                                      \
        for (int qt = 0; qt < 2; ++qt)                                         \
            _Pragma("unroll")                                                  \
            for (int kj = 0; kj < 4; ++kj)                                     \
                s[qt][kj] = (f32x4){0.f, 0.f, 0.f, 0.f};                       \
        __builtin_amdgcn_s_setprio(1);                                         \
        _Pragma("unroll")                                                      \
        for (int ks = 0; ks < 2; ++ks) {                                       \
            const int sl = ((ks * 4 + g) ^ r7) * 8;                            \
            bf16x8 ak[4];                                                      \
            _Pragma("unroll")                                                  \
            for (int kj = 0; kj < 4; ++kj)                                     \
                ak[kj] = *(const bf16x8*)(&Ks[CUR][kj * 16 + rsel][sl]);       \
            _Pragma("unroll")                                                  \
            for (int qt = 0; qt < 2; ++qt)                                     \
                _Pragma("unroll")                                              \
                for (int kj = 0; kj < 4; ++kj)                                 \
                    s[qt][kj] = mfma16(ak[kj], bq[qt][ks], s[qt][kj]);         \
        }                                                                      \
        __builtin_amdgcn_s_setprio(0);                                         \
        _Pragma("unroll")                                                      \
        for (int qt = 0; qt < 2; ++qt)                                         \
            _Pragma("unroll")                                                  \
            for (int kj = 0; kj < 4; ++kj) {                                   \
                float p0 = __builtin_amdgcn_exp2f(s[qt][kj][0]);               \
                float p1 = __builtin_amdgcn_exp2f(s[qt][kj][1]);               \
                float p2 = __builtin_amdgcn_exp2f(s[qt][kj][2]);               \
                float p3 = __builtin_amdgcn_exp2f(s[qt][kj][3]);               \
                union { __hip_bfloat162 h2[2]; uint2 u; } pk;                  \
                pk.h2[0] = __float22bfloat162_rn(make_float2(p0, p1));         \
                pk.h2[1] = __float22bfloat162_rn(make_float2(p2, p3));         \
                const int slot16 = (kj * 2 + (g >> 1)) ^ r7;                   \
                *(uint2*)(&Ps[wid][qt * 16 + rsel][slot16 * 8 + (g & 1) * 4])  \
                    = pk.u;                                                    \
            }                                                                  \
        __builtin_amdgcn_s_setprio(1);                                         \
        _Pragma("unroll")                                                      \
        for (int ks = 0; ks < 2; ++ks) {                                       \
            const int sl = ((ks * 4 + g) ^ r7) * 8;                            \
            bf16x8 pa0 = *(const bf16x8*)(&Ps[wid][rsel][sl]);                 \
            bf16x8 pa1 = *(const bf16x8*)(&Ps[wid][16 + rsel][sl]);            \
            bf16x8 vb[4];                                                      \
            _Pragma("unroll")                                                  \
            for (int dj = 0; dj < 4; ++dj)                                     \
                vb[dj] = *(const bf16x8*)(&Vs[CUR][dj * 16 + rsel][sl]);       \
            _Pragma("unroll")                                                  \
            for (int dj = 0; dj < 4; ++dj) {                                   \
                o[0][dj] = mfma16(pa0, vb[dj], o[0][dj]);                      \
                o[1][dj] = mfma16(pa1, vb[dj], o[1][dj]);                      \
            }                                                                  \
            ol[0] = mfma16(pa0, ones, ol[0]);                                  \
            ol[1] = mfma16(pa1, ones, ol[1]);                                  \
        }                                                                      \
        __builtin_amdgcn_s_setprio(0);                                         \
        asm volatile("s_waitcnt vmcnt(0)" ::: "memory");                       \
        __syncthreads();                                                       \
    }

#pragma unroll 1
    for (int i = 0; i < 16; ++i) {
        BODY(0, 1, true);        // kt = 2i   (prefetch 2i+1, always valid)
        BODY(1, 0, (i < 15));    // kt = 2i+1 (prefetch 2i+2 unless last)
    }
#undef BODY

    // epilogue: beta*softmax + alpha*V[q] - gamma/n * vsum
    const float alpha = *alpha_p, beta = *beta_p;
    const float gn = (*gamma_p) / 2048.0f;
#pragma unroll
    for (int qt = 0; qt < 2; ++qt) {
        float linv[4];
#pragma unroll
        for (int r = 0; r < 4; ++r)
            linv[r] = beta / ol[qt][r];
#pragma unroll
        for (int dj = 0; dj < 4; ++dj)
#pragma unroll
            for (int r = 0; r < 4; ++r) {
                int qrow = q0 + wq0 + qt * 16 + g4 + r;
                int dv = dj * 16 + rsel;
                float ov = o[qt][dj][r] * linv[r];
                float vdiag = bf2f(qkv[(size_t)(b * 2048 + qrow) * 3072 + 2048 + h * 64 + dv]);
                float vs = vsum[bh * 64 + dv];
                float res = ov + alpha * vdiag - gn * vs;
                AO[(size_t)(b * 2048 + qrow) * 1024 + h * 64 + dv] = f2bf(res);
            }
    }
}

// ---------------------------------------------------------------------------
// GEMM2: out f32[4096][1024] = AO bf16 @ Wt2^T + bias.  64x128 tile,
// grid 8x64 = 512 blocks = 2 blocks/CU (was 1 -- no TLP to hide latency).
// ---------------------------------------------------------------------------
__global__ __launch_bounds__(256) void k_gemm2(
    const unsigned short* __restrict__ A, const unsigned short* __restrict__ B,
    const float* __restrict__ bias, float* __restrict__ Out)
{
    __shared__ unsigned short As[64 * 64];
    __shared__ unsigned short Bs[128 * 64];
    const int tid = threadIdx.x, lane = tid & 63, wid = tid >> 6;
    const int wr = (wid >> 1) * 32, wc = (wid & 1) * 64;
    const int row0 = blockIdx.y * 64, col0 = blockIdx.x * 128;
    const int rsel = lane & 15, kgr = (lane >> 4) * 8;
    const int lr = lane >> 3, lc = (lane & 7) * 8;

    f32x4 acc[2][4];
#pragma unroll
    for (int i = 0; i < 2; ++i)
#pragma unroll
        for (int j = 0; j < 4; ++j) acc[i][j] = (f32x4){0.f, 0.f, 0.f, 0.f};

    for (int k0 = 0; k0 < 1024; k0 += 64) {
        __syncthreads();
#pragma unroll
        for (int i = 0; i < 2; ++i) {
            int rb = wid * 8 + i * 32;
            gload_lds16(A + (size_t)(row0 + rb + lr) * 1024 + k0 + lc, As + rb * 64);
        }
#pragma unroll
        for (int i = 0; i < 4; ++i) {
            int rb = wid * 8 + i * 32;
            gload_lds16(B + (size_t)(col0 + rb + lr) * 1024 + k0 + lc, Bs + rb * 64);
        }
        __syncthreads();
#pragma unroll
        for (int ks = 0; ks < 2; ++ks) {
            bf16x8 a[2], b[4];
            int ko = ks * 32 + kgr;
#pragma unroll
            for (int mi = 0; mi < 2; ++mi)
                a[mi] = *(const bf16x8*)(As + (wr + mi * 16 + rsel) * 64 + ko);
#pragma unroll
            for (int nj = 0; nj < 4; ++nj)
                b[nj] = *(const bf16x8*)(Bs + (wc + nj * 16 + rsel) * 64 + ko);
#pragma unroll
            for (int mi = 0; mi < 2; ++mi)
#pragma unroll
                for (int nj = 0; nj < 4; ++nj)
                    acc[mi][nj] = mfma16(a[mi], b[nj], acc[mi][nj]);
        }
    }
    const int rbase = row0 + wr + ((lane >> 4) << 2);
    const int cbase = col0 + wc + rsel;
#pragma unroll
    for (int mi = 0; mi < 2; ++mi)
#pragma unroll
        for (int nj = 0; nj < 4; ++nj) {
            int gc = cbase + nj * 16;
            float bv = bias[gc];
#pragma unroll
            for (int r = 0; r < 4; ++r)
                Out[(size_t)(rbase + mi * 16 + r) * 1024 + gc] = acc[mi][nj][r] + bv;
        }
}

// ---------------------------------------------------------------------------
extern "C" void kernel_launch(void* const* d_in, const int* in_sizes, int n_in,
                              void* d_out, int out_size, void* d_ws, size_t ws_size,
                              hipStream_t stream) {
    const float* x     = (const float*)d_in[0];
    const float* Wqkv  = (const float*)d_in[1];
    const float* Wout  = (const float*)d_in[2];
    const float* bout  = (const float*)d_in[3];
    const float* alpha = (const float*)d_in[4];
    const float* beta  = (const float*)d_in[5];
    const float* gamma = (const float*)d_in[6];
    float* out = (float*)d_out;

    char* ws = (char*)d_ws;
    unsigned short* Xb  = (unsigned short*)(ws);               // 8 MB (reused as AO)
    unsigned short* Wt1 = (unsigned short*)(ws + 8388608);     // 6 MB
    unsigned short* Wt2 = (unsigned short*)(ws + 14680064);    // 2 MB
    unsigned short* qkv = (unsigned short*)(ws + 16777216);    // 24 MB
    unsigned short* Vt  = (unsigned short*)(ws + 41943040);    // 8 MB
    float* vsum         = (float*)(ws + 50331648);             // 8 KB
    unsigned short* AO  = Xb;   // Xb dead after k_gemm1

    hipMemsetAsync(vsum, 0, 2048 * sizeof(float), stream);
    k_prep<<<2048, 256, 0, stream>>>(x, Wqkv, Wout, Xb, Wt1, Wt2);
    k_gemm1<<<dim3(24, 32), 256, 0, stream>>>(Xb, Wt1, qkv);
    k_vt<<<dim3(32, 32), 256, 0, stream>>>(qkv, Vt, vsum);
    k_attn<<<512, 256, 0, stream>>>(qkv, Vt, vsum, alpha, beta, gamma, AO);
    k_gemm2<<<dim3(8, 64), 256, 0, stream>>>(AO, Wt2, bout, out);
}

// Round 12
// 143.037 us; speedup vs baseline: 1.2463x; 1.0071x over previous
//
#include <hip/hip_runtime.h>
#include <hip/hip_bf16.h>

#define DEVI __device__ __forceinline__

typedef __attribute__((ext_vector_type(8))) short bf16x8;
typedef __attribute__((ext_vector_type(4))) short bf16x4;
typedef __attribute__((ext_vector_type(4))) float f32x4;

DEVI unsigned short f2bf(float f) {
    unsigned u = __float_as_uint(f);
    u += 0x7FFF + ((u >> 16) & 1);
    return (unsigned short)(u >> 16);
}
DEVI float bf2f(unsigned short h) {
    return __uint_as_float(((unsigned)h) << 16);
}
DEVI f32x4 mfma16(bf16x8 a, bf16x8 b, f32x4 c) {
    return __builtin_amdgcn_mfma_f32_16x16x32_bf16(a, b, c, 0, 0, 0);
}
DEVI void gload_lds16(const void* g, void* l) {
    __builtin_amdgcn_global_load_lds(
        (const __attribute__((address_space(1))) unsigned int*)g,
        (__attribute__((address_space(3))) unsigned int*)l, 16, 0, 0);
}

// ---------------------------------------------------------------------------
// Fused prep: blocks [0,1024) convert X f32->bf16; [1024,1792) transpose
// W_qkv (Q-columns pre-scaled by log2(e)/32); [1792,2048) transpose W_out.
// ---------------------------------------------------------------------------
DEVI void wt_body(const float* __restrict__ W, unsigned short* __restrict__ Wt,
                  int N, int n0, int k0, float sc, int tid,
                  unsigned short (*T)[72])
{
#pragma unroll
    for (int j = 0; j < 4; ++j) {
        int idx = tid + j * 256;
        int kk = idx >> 4, c4 = (idx & 15) << 2;
        float4 v = *(const float4*)(W + (size_t)(k0 + kk) * N + n0 + c4);
        T[c4 + 0][kk] = f2bf(v.x * sc); T[c4 + 1][kk] = f2bf(v.y * sc);
        T[c4 + 2][kk] = f2bf(v.z * sc); T[c4 + 3][kk] = f2bf(v.w * sc);
    }
    __syncthreads();
#pragma unroll
    for (int j = 0; j < 4; ++j) {
        int idx = tid + j * 256;
        int n = idx >> 4, c4 = (idx & 15) << 2;
        *(bf16x4*)(Wt + (size_t)(n0 + n) * 1024 + k0 + c4) = *(bf16x4*)&T[n][c4];
    }
}

__global__ __launch_bounds__(256) void k_prep(
    const float* __restrict__ X, const float* __restrict__ Wqkv,
    const float* __restrict__ Wout,
    unsigned short* __restrict__ Xb, unsigned short* __restrict__ Wt1,
    unsigned short* __restrict__ Wt2)
{
    __shared__ unsigned short T[64][72];
    const int tid = threadIdx.x;
    const int bid = blockIdx.x;
    const float QSC = 1.4426950408889634f / 32.0f;
    if (bid < 1024) {
        int i = bid * 256 + tid;
#pragma unroll
        for (int j = 0; j < 4; ++j) {
            int idx = i + j * 262144;
            float4 v = *(const float4*)(X + (size_t)idx * 4);
            bf16x4 hv;
            hv[0] = (short)f2bf(v.x); hv[1] = (short)f2bf(v.y);
            hv[2] = (short)f2bf(v.z); hv[3] = (short)f2bf(v.w);
            *(bf16x4*)(Xb + (size_t)idx * 4) = hv;
        }
    } else if (bid < 1792) {
        int idx = bid - 1024;
        int n0 = (idx % 48) * 64, k0 = (idx / 48) * 64;
        wt_body(Wqkv, Wt1, 3072, n0, k0, (n0 < 1024) ? QSC : 1.0f, tid, T);
    } else {
        int idx = bid - 1792;
        int n0 = (idx & 15) * 64, k0 = (idx >> 4) * 64;
        wt_body(Wout, Wt2, 1024, n0, k0, 1.0f, tid, T);
    }
}

// ---------------------------------------------------------------------------
// GEMM1: qkv[4096][3072] bf16 = Xb[4096][1024] @ Wt1^T.  Epilogue stages the
// C-tile through LDS for coalesced bf16x8 stores.  Shared block is 36 KB:
// staging needs 2x8192 shorts, epilogue needs 4 waves x 64 x 72 = 18432.
// ---------------------------------------------------------------------------
__global__ __launch_bounds__(256) void k_gemm1(
    const unsigned short* __restrict__ A, const unsigned short* __restrict__ B,
    unsigned short* __restrict__ C)
{
    __shared__ unsigned short Sh[18432];   // 36 KB
    unsigned short* As = Sh;
    unsigned short* Bs = Sh + 8192;
    const int tid = threadIdx.x, lane = tid & 63, wid = tid >> 6;
    const int wr = (wid >> 1) * 64, wc = (wid & 1) * 64;
    const int row0 = blockIdx.y * 128, col0 = blockIdx.x * 128;
    const int rsel = lane & 15, kgr = (lane >> 4) * 8;
    const int lr = lane >> 3, lc = (lane & 7) * 8;

    f32x4 acc[4][4];
#pragma unroll
    for (int i = 0; i < 4; ++i)
#pragma unroll
        for (int j = 0; j < 4; ++j) acc[i][j] = (f32x4){0.f, 0.f, 0.f, 0.f};

    for (int k0 = 0; k0 < 1024; k0 += 64) {
        __syncthreads();
#pragma unroll
        for (int i = 0; i < 4; ++i) {
            int rb = wid * 32 + i * 8;
            gload_lds16(A + (size_t)(row0 + rb + lr) * 1024 + k0 + lc, As + rb * 64);
            gload_lds16(B + (size_t)(col0 + rb + lr) * 1024 + k0 + lc, Bs + rb * 64);
        }
        __syncthreads();
#pragma unroll
        for (int ks = 0; ks < 2; ++ks) {
            bf16x8 a[4], b[4];
            int ko = ks * 32 + kgr;
#pragma unroll
            for (int mi = 0; mi < 4; ++mi)
                a[mi] = *(const bf16x8*)(As + (wr + mi * 16 + rsel) * 64 + ko);
#pragma unroll
            for (int nj = 0; nj < 4; ++nj)
                b[nj] = *(const bf16x8*)(Bs + (wc + nj * 16 + rsel) * 64 + ko);
#pragma unroll
            for (int mi = 0; mi < 4; ++mi)
#pragma unroll
                for (int nj = 0; nj < 4; ++nj)
                    acc[mi][nj] = mfma16(a[mi], b[nj], acc[mi][nj]);
        }
    }
    // epilogue: per-wave 64x64 C-quadrant via LDS (72-padded), coalesced store
    __syncthreads();   // all staging reads done before overwrite
    unsigned short (*wb)[72] = (unsigned short (*)[72])(Sh + wid * 4608);
    const int g4 = (lane >> 4) << 2;
#pragma unroll
    for (int mi = 0; mi < 4; ++mi)
#pragma unroll
        for (int nj = 0; nj < 4; ++nj)
#pragma unroll
            for (int r = 0; r < 4; ++r)
                wb[mi * 16 + g4 + r][nj * 16 + rsel] = f2bf(acc[mi][nj][r]);
#pragma unroll
    for (int rr = 0; rr < 8; ++rr) {
        int row = rr * 8 + (lane >> 3);
        int c8 = (lane & 7) * 8;
        bf16x8 v = *(const bf16x8*)&wb[row][c8];
        *(bf16x8*)(C + (size_t)(row0 + wr + row) * 3072 + col0 + wc + c8) = v;
    }
}

// ---------------------------------------------------------------------------
// Build Vt[bh][64][2048] from qkv V-section via LDS transpose; fused vsum
// partial column-sums (atomicAdd; vsum zeroed by host-side memsetAsync).
// ---------------------------------------------------------------------------
__global__ __launch_bounds__(256) void k_vt(
    const unsigned short* __restrict__ qkv, unsigned short* __restrict__ Vt,
    float* __restrict__ vsum)
{
    __shared__ unsigned short T[64][72];   // [n][dv]
    __shared__ float ps[64];
    const int tid = threadIdx.x, lane = tid & 63, wid = tid >> 6;
    const int bh = blockIdx.y, b = bh >> 4, h = bh & 15;
    const int n0 = blockIdx.x * 64;
    const unsigned short* src = qkv + (size_t)(b * 2048 + n0) * 3072 + 2048 + h * 64;
#pragma unroll
    for (int j = 0; j < 2; ++j) {
        int idx = tid + j * 256;
        int n = idx >> 3, c8 = (idx & 7) << 3;
        *(bf16x8*)&T[n][c8] = *(const bf16x8*)(src + (size_t)n * 3072 + c8);
    }
    if (tid < 64) ps[tid] = 0.f;
    __syncthreads();
#pragma unroll
    for (int i = 0; i < 16; ++i) {
        int dv = wid * 16 + i;
        Vt[((size_t)bh * 64 + dv) * 2048 + n0 + lane] = T[lane][dv];
    }
    {
        const int col = tid & 63, qtr = tid >> 6;
        float s = 0.f;
#pragma unroll
        for (int i = 0; i < 16; ++i) s += bf2f(T[qtr * 16 + i][col]);
        atomicAdd(&ps[col], s);
        __syncthreads();
        if (tid < 64) atomicAdd(&vsum[bh * 64 + tid], ps[tid]);
    }
}

// ---------------------------------------------------------------------------
// Flash attention, q-tile 128 (nq=2), grid 512, XCD swizzle. exp2-only
// softmax.  2-tile pipeline: quad-buffered K/V (80 KB LDS), one
// vmcnt(0)+barrier per PAIR of KV tiles (halves sync count), two independent
// dep chains per pair so exp2/pack VALU hides under the other tile's MFMAs.
// ---------------------------------------------------------------------------
__global__ __launch_bounds__(256) void k_attn(
    const unsigned short* __restrict__ qkv, const unsigned short* __restrict__ Vt,
    const float* __restrict__ vsum,
    const float* __restrict__ alpha_p, const float* __restrict__ beta_p,
    const float* __restrict__ gamma_p,
    unsigned short* __restrict__ AO)
{
    __shared__ unsigned short Ks[4][64][64];   // linear, swizzled content
    __shared__ unsigned short Vs[4][64][64];   // linear, swizzled content
    __shared__ unsigned short Ps[4][32][64];   // per-wave, 16B-slot XOR swizzle
    const int tid = threadIdx.x, lane = tid & 63, wid = tid >> 6;
    // bijective XCD swizzle: nwg=512, 64 consecutive logical blocks per XCD
    const int swz = (blockIdx.x & 7) * 64 + (blockIdx.x >> 3);
    const int bh = swz >> 4, qtb = swz & 15;
    const int b = bh >> 4, h = bh & 15;
    const int q0 = qtb * 128;
    const int rsel = lane & 15, g = lane >> 4;
    const int g4 = g << 2;
    const int wq0 = wid * 32;
    const int r7 = rsel & 7;

    // Q fragments in registers (already pre-scaled by log2(e)/32 in prep)
    bf16x8 bq[2][2];
#pragma unroll
    for (int qt = 0; qt < 2; ++qt) {
        const unsigned short* qrow =
            qkv + (size_t)(b * 2048 + q0 + wq0 + qt * 16 + rsel) * 3072 + h * 64;
        bq[qt][0] = *(const bf16x8*)(qrow + g * 8);
        bq[qt][1] = *(const bf16x8*)(qrow + 32 + g * 8);
    }

    // incremental staging pointers (inverse-swizzled source slots)
    const int sr = lane >> 3;                 // 0..7 within 8-row slab
    const int ss = (lane & 7) ^ sr;           // 16B slot in global row
    const int rb0 = wid * 16, rb1 = wid * 16 + 8;
    const unsigned short* kp0 = qkv + (size_t)(b * 2048) * 3072 + 1024 + h * 64
                              + (size_t)(rb0 + sr) * 3072 + ss * 8;
    const unsigned short* kp1 = kp0 + (size_t)8 * 3072;
    const unsigned short* vp0 = Vt + (size_t)bh * 64 * 2048
                              + (size_t)(rb0 + sr) * 2048 + ss * 8;
    const unsigned short* vp1 = vp0 + (size_t)8 * 2048;
    const size_t KADV = (size_t)64 * 3072;

    f32x4 o[2][4], ol[2];
#pragma unroll
    for (int qt = 0; qt < 2; ++qt) {
#pragma unroll
        for (int dj = 0; dj < 4; ++dj) o[qt][dj] = (f32x4){0.f, 0.f, 0.f, 0.f};
        ol[qt] = (f32x4){0.f, 0.f, 0.f, 0.f};
    }
    bf16x8 ones;
#pragma unroll
    for (int e = 0; e < 8; ++e) ones[e] = (short)0x3F80;   // bf16 1.0

#define STAGE(BUF)                                                             \
    {                                                                          \
        gload_lds16(kp0, &Ks[BUF][rb0][0]);                                    \
        gload_lds16(kp1, &Ks[BUF][rb1][0]);                                    \
        gload_lds16(vp0, &Vs[BUF][rb0][0]);                                    \
        gload_lds16(vp1, &Vs[BUF][rb1][0]);                                    \
        kp0 += KADV; kp1 += KADV; vp0 += 64; vp1 += 64;                        \
    }

    // prologue: stage tiles 0,1 into bufs 0,1
    STAGE(0); STAGE(1);
    asm volatile("s_waitcnt vmcnt(0)" ::: "memory");
    __syncthreads();

#define QK(CUR, S)                                                             \
    {                                                                          \
        _Pragma("unroll")                                                      \
        for (int qt = 0; qt < 2; ++qt)                                         \
            _Pragma("unroll")                                                  \
            for (int kj = 0; kj < 4; ++kj)                                     \
                S[qt][kj] = (f32x4){0.f, 0.f, 0.f, 0.f};                       \
        __builtin_amdgcn_s_setprio(1);                                         \
        _Pragma("unroll")                                                      \
        for (int ks = 0; ks < 2; ++ks) {                                       \
            const int sl = ((ks * 4 + g) ^ r7) * 8;                            \
            bf16x8 ak[4];                                                      \
            _Pragma("unroll")                                                  \
            for (int kj = 0; kj < 4; ++kj)                                     \
                ak[kj] = *(const bf16x8*)(&Ks[CUR][kj * 16 + rsel][sl]);       \
            _Pragma("unroll")                                                  \
            for (int qt = 0; qt < 2; ++qt)                                     \
                _Pragma("unroll")                                              \
                for (int kj = 0; kj < 4; ++kj)                                 \
                    S[qt][kj] = mfma16(ak[kj], bq[qt][ks], S[qt][kj]);         \
        }                                                                      \
        __builtin_amdgcn_s_setprio(0);                                         \
    }

#define EPV(CUR, S)                                                            \
    {                                                                          \
        _Pragma("unroll")                                                      \
        for (int qt = 0; qt < 2; ++qt)                                         \
            _Pragma("unroll")                                                  \
            for (int kj = 0; kj < 4; ++kj) {                                   \
                float p0 = __builtin_amdgcn_exp2f(S[qt][kj][0]);               \
                float p1 = __builtin_amdgcn_exp2f(S[qt][kj][1]);               \
                float p2 = __builtin_amdgcn_exp2f(S[qt][kj][2]);               \
                float p3 = __builtin_amdgcn_exp2f(S[qt][kj][3]);               \
                union { __hip_bfloat162 h2[2]; uint2 u; } pk;                  \
                pk.h2[0] = __float22bfloat162_rn(make_float2(p0, p1));         \
                pk.h2[1] = __float22bfloat162_rn(make_float2(p2, p3));         \
                const int slot16 = (kj * 2 + (g >> 1)) ^ r7;                   \
                *(uint2*)(&Ps[wid][qt * 16 + rsel][slot16 * 8 + (g & 1) * 4])  \
                    = pk.u;                                                    \
            }                                                                  \
        __builtin_amdgcn_s_setprio(1);                                         \
        _Pragma("unroll")                                                      \
        for (int ks = 0; ks < 2; ++ks) {                                       \
            const int sl = ((ks * 4 + g) ^ r7) * 8;                            \
            bf16x8 pa0 = *(const bf16x8*)(&Ps[wid][rsel][sl]);                 \
            bf16x8 pa1 = *(const bf16x8*)(&Ps[wid][16 + rsel][sl]);            \
            bf16x8 vb[4];                                                      \
            _Pragma("unroll")                                                  \
            for (int dj = 0; dj < 4; ++dj)                                     \
                vb[dj] = *(const bf16x8*)(&Vs[CUR][dj * 16 + rsel][sl]);       \
            _Pragma("unroll")                                                  \
            for (int dj = 0; dj < 4; ++dj) {                                   \
                o[0][dj] = mfma16(pa0, vb[dj], o[0][dj]);                      \
                o[1][dj] = mfma16(pa1, vb[dj], o[1][dj]);                      \
            }                                                                  \
            ol[0] = mfma16(pa0, ones, ol[0]);                                  \
            ol[1] = mfma16(pa1, ones, ol[1]);                                  \
        }                                                                      \
        __builtin_amdgcn_s_setprio(0);                                         \
    }

#define PAIR(C0, C1, DOPF)                                                     \
    {                                                                          \
        f32x4 s0[2][4], s1[2][4];                                              \
        if (DOPF) { STAGE(C0 ^ 2); STAGE(C1 ^ 2); }                            \
        QK(C0, s0);                                                            \
        QK(C1, s1);                                                            \
        EPV(C0, s0);                                                           \
        EPV(C1, s1);                                                           \
        asm volatile("s_waitcnt vmcnt(0)" ::: "memory");                       \
        __syncthreads();                                                       \
    }

#pragma unroll 1
    for (int i = 0; i < 8; ++i) {
        PAIR(0, 1, true);          // tiles 4i,4i+1; prefetch 4i+2,4i+3
        PAIR(2, 3, (i < 7));       // tiles 4i+2,4i+3; prefetch 4i+4,4i+5
    }
#undef PAIR
#undef EPV
#undef QK
#undef STAGE

    // epilogue: beta*softmax + alpha*V[q] - gamma/n * vsum
    const float alpha = *alpha_p, beta = *beta_p;
    const float gn = (*gamma_p) / 2048.0f;
#pragma unroll
    for (int qt = 0; qt < 2; ++qt) {
        float linv[4];
#pragma unroll
        for (int r = 0; r < 4; ++r)
            linv[r] = beta / ol[qt][r];
#pragma unroll
        for (int dj = 0; dj < 4; ++dj)
#pragma unroll
            for (int r = 0; r < 4; ++r) {
                int qrow = q0 + wq0 + qt * 16 + g4 + r;
                int dv = dj * 16 + rsel;
                float ov = o[qt][dj][r] * linv[r];
                float vdiag = bf2f(qkv[(size_t)(b * 2048 + qrow) * 3072 + 2048 + h * 64 + dv]);
                float vs = vsum[bh * 64 + dv];
                float res = ov + alpha * vdiag - gn * vs;
                AO[(size_t)(b * 2048 + qrow) * 1024 + h * 64 + dv] = f2bf(res);
            }
    }
}

// ---------------------------------------------------------------------------
// GEMM2: out f32[4096][1024] = AO bf16 @ Wt2^T + bias.  64x128 tile,
// grid 8x64 = 512 blocks = 2 blocks/CU.
// ---------------------------------------------------------------------------
__global__ __launch_bounds__(256) void k_gemm2(
    const unsigned short* __restrict__ A, const unsigned short* __restrict__ B,
    const float* __restrict__ bias, float* __restrict__ Out)
{
    __shared__ unsigned short As[64 * 64];
    __shared__ unsigned short Bs[128 * 64];
    const int tid = threadIdx.x, lane = tid & 63, wid = tid >> 6;
    const int wr = (wid >> 1) * 32, wc = (wid & 1) * 64;
    const int row0 = blockIdx.y * 64, col0 = blockIdx.x * 128;
    const int rsel = lane & 15, kgr = (lane >> 4) * 8;
    const int lr = lane >> 3, lc = (lane & 7) * 8;

    f32x4 acc[2][4];
#pragma unroll
    for (int i = 0; i < 2; ++i)
#pragma unroll
        for (int j = 0; j < 4; ++j) acc[i][j] = (f32x4){0.f, 0.f, 0.f, 0.f};

    for (int k0 = 0; k0 < 1024; k0 += 64) {
        __syncthreads();
#pragma unroll
        for (int i = 0; i < 2; ++i) {
            int rb = wid * 8 + i * 32;
            gload_lds16(A + (size_t)(row0 + rb + lr) * 1024 + k0 + lc, As + rb * 64);
        }
#pragma unroll
        for (int i = 0; i < 4; ++i) {
            int rb = wid * 8 + i * 32;
            gload_lds16(B + (size_t)(col0 + rb + lr) * 1024 + k0 + lc, Bs + rb * 64);
        }
        __syncthreads();
#pragma unroll
        for (int ks = 0; ks < 2; ++ks) {
            bf16x8 a[2], b[4];
            int ko = ks * 32 + kgr;
#pragma unroll
            for (int mi = 0; mi < 2; ++mi)
                a[mi] = *(const bf16x8*)(As + (wr + mi * 16 + rsel) * 64 + ko);
#pragma unroll
            for (int nj = 0; nj < 4; ++nj)
                b[nj] = *(const bf16x8*)(Bs + (wc + nj * 16 + rsel) * 64 + ko);
#pragma unroll
            for (int mi = 0; mi < 2; ++mi)
#pragma unroll
                for (int nj = 0; nj < 4; ++nj)
                    acc[mi][nj] = mfma16(a[mi], b[nj], acc[mi][nj]);
        }
    }
    const int rbase = row0 + wr + ((lane >> 4) << 2);
    const int cbase = col0 + wc + rsel;
#pragma unroll
    for (int mi = 0; mi < 2; ++mi)
#pragma unroll
        for (int nj = 0; nj < 4; ++nj) {
            int gc = cbase + nj * 16;
            float bv = bias[gc];
#pragma unroll
            for (int r = 0; r < 4; ++r)
                Out[(size_t)(rbase + mi * 16 + r) * 1024 + gc] = acc[mi][nj][r] + bv;
        }
}

// ---------------------------------------------------------------------------
extern "C" void kernel_launch(void* const* d_in, const int* in_sizes, int n_in,
                              void* d_out, int out_size, void* d_ws, size_t ws_size,
                              hipStream_t stream) {
    const float* x     = (const float*)d_in[0];
    const float* Wqkv  = (const float*)d_in[1];
    const float* Wout  = (const float*)d_in[2];
    const float* bout  = (const float*)d_in[3];
    const float* alpha = (const float*)d_in[4];
    const float* beta  = (const float*)d_in[5];
    const float* gamma = (const float*)d_in[6];
    float* out = (float*)d_out;

    char* ws = (char*)d_ws;
    unsigned short* Xb  = (unsigned short*)(ws);               // 8 MB (reused as AO)
    unsigned short* Wt1 = (unsigned short*)(ws + 8388608);     // 6 MB
    unsigned short* Wt2 = (unsigned short*)(ws + 14680064);    // 2 MB
    unsigned short* qkv = (unsigned short*)(ws + 16777216);    // 24 MB
    unsigned short* Vt  = (unsigned short*)(ws + 41943040);    // 8 MB
    float* vsum         = (float*)(ws + 50331648);             // 8 KB
    unsigned short* AO  = Xb;   // Xb dead after k_gemm1

    hipMemsetAsync(vsum, 0, 2048 * sizeof(float), stream);
    k_prep<<<2048, 256, 0, stream>>>(x, Wqkv, Wout, Xb, Wt1, Wt2);
    k_gemm1<<<dim3(24, 32), 256, 0, stream>>>(Xb, Wt1, qkv);
    k_vt<<<dim3(32, 32), 256, 0, stream>>>(qkv, Vt, vsum);
    k_attn<<<512, 256, 0, stream>>>(qkv, Vt, vsum, alpha, beta, gamma, AO);
    k_gemm2<<<dim3(8, 64), 256, 0, stream>>>(AO, Wt2, bout, out);
}